// Round 8
// baseline (486.953 us; speedup 1.0000x reference)
//
#include <hip/hip_runtime.h>

#define N_NODES 100000
#define N_EDGES 1600000
#define NB 391          // coarse buckets of 256 nodes
#define BCAP 5120       // per-bucket capacity (expected 4096, 16-sigma headroom)
#define PART_BLOCKS 250
#define EPB 6400        // edges per partition block (250*6400 = 1.6M exact)
#define NSLICE 13       // src slices of 8192 nodes (2 MB of xb each, < 4 MiB L2)
#define SLICE_SHIFT 13
#define NWAVES 8192     // persistent agg kernels: 2048 blocks x 4 waves = 32 waves/CU

typedef __attribute__((ext_vector_type(8))) short short8;   // 8 bf16 (4 VGPR) MFMA frag
typedef __attribute__((ext_vector_type(4))) float f32x4;    // MFMA accumulator

__device__ inline unsigned short f2bf(float f) {
    unsigned int u = __builtin_bit_cast(unsigned int, f);
    u += 0x7fffu + ((u >> 16) & 1u);   // round-to-nearest-even
    return (unsigned short)(u >> 16);
}
__device__ inline float bf2f(unsigned short h) {
    unsigned int u = ((unsigned int)h) << 16;
    return __builtin_bit_cast(float, u);
}

// ---- xb = bf16(x * out_norm[row]) ----
__global__ __launch_bounds__(256) void k_xb(const float* __restrict__ x, const float* __restrict__ out_norm,
                                            unsigned short* __restrict__ xb) {
    int tid = blockIdx.x * 256 + threadIdx.x;   // grid exactly N*32
    int row = tid >> 5;
    float4 v = ((const float4*)x)[tid];
    float w = out_norm[row];
    unsigned int lo = (unsigned int)f2bf(v.x * w) | ((unsigned int)f2bf(v.y * w) << 16);
    unsigned int hi = (unsigned int)f2bf(v.z * w) | ((unsigned int)f2bf(v.w * w) << 16);
    ((uint2*)xb)[tid] = make_uint2(lo, hi);
}

// ---- pack W1/W2 (f32) into bf16 B-fragment layout: entry (kq, c) = W[kq*8+j][c], j=0..7 ----
__global__ __launch_bounds__(256) void k_pack_w(const float* __restrict__ W1, const float* __restrict__ W2,
                                                unsigned short* __restrict__ Wp1, unsigned short* __restrict__ Wp2) {
    int i = blockIdx.x * 256 + threadIdx.x;   // 3072 total
    if (i < 2048) {                           // W1: 16 kq x 128 c
        int kq = i >> 7, c = i & 127;
#pragma unroll
        for (int j = 0; j < 8; j++) Wp1[i * 8 + j] = f2bf(W1[(kq * 8 + j) * 128 + c]);
    } else if (i < 3072) {                    // W2: 16 kq x 64 c
        int i2 = i - 2048;
        int kq = i2 >> 6, c = i2 & 63;
#pragma unroll
        for (int j = 0; j < 8; j++) Wp2[i2 * 8 + j] = f2bf(W2[(kq * 8 + j) * 64 + c]);
    }
}

// ---- partition: dst-keyed buckets (full edge) + src-keyed buckets (1 byte) ----
__global__ __launch_bounds__(256) void k_part(const int* __restrict__ src, const int* __restrict__ dst,
                                              int* __restrict__ gcurD, int* __restrict__ gcurS,
                                              unsigned int* __restrict__ ebuf,
                                              unsigned char* __restrict__ ebufS) {
    __shared__ int histD[NB], gbaseD[NB];
    __shared__ int histS[NB], gbaseS[NB];
    for (int i = threadIdx.x; i < NB; i += 256) { histD[i] = 0; histS[i] = 0; }
    __syncthreads();
    int base = blockIdx.x * EPB;
    for (int i = threadIdx.x; i < EPB; i += 256) {
        int d = dst[base + i], s = src[base + i];
        atomicAdd(&histD[d >> 8], 1);
        atomicAdd(&histS[s >> 8], 1);
    }
    __syncthreads();
    for (int i = threadIdx.x; i < NB; i += 256) {
        gbaseD[i] = atomicAdd(&gcurD[i], histD[i]);
        gbaseS[i] = atomicAdd(&gcurS[i], histS[i]);
        histD[i] = 0;                          // reuse as local run cursors
        histS[i] = 0;
    }
    __syncthreads();
    for (int i = threadIdx.x; i < EPB; i += 256) {
        int d = dst[base + i], s = src[base + i];
        int bd = d >> 8;
        int r = atomicAdd(&histD[bd], 1);
        int pos = gbaseD[bd] + r;
        if (pos < BCAP) ebuf[(size_t)bd * BCAP + pos] = ((unsigned int)s << 8) | (unsigned int)(d & 255);
        int bs = s >> 8;
        int r2 = atomicAdd(&histS[bs], 1);
        int pos2 = gbaseS[bs] + r2;
        if (pos2 < BCAP) ebufS[(size_t)bs * BCAP + pos2] = (unsigned char)(s & 255);
    }
}

// ---- per-bucket out-degree histogram -> out_norm ----
__global__ __launch_bounds__(256) void k_bhist(const unsigned char* __restrict__ ebufS,
                                               const int* __restrict__ gcurS,
                                               float* __restrict__ out_norm) {
    __shared__ int hist[256];
    int b = blockIdx.x, t = threadIdx.x;
    hist[t] = 0;
    __syncthreads();
    int ne = min(gcurS[b], BCAP);
    const unsigned char* eb = ebufS + (size_t)b * BCAP;
    for (int i = t; i < ne; i += 256) atomicAdd(&hist[eb[i]], 1);
    __syncthreads();
    int node = b * 256 + t;
    if (node < N_NODES) out_norm[node] = hist[t] > 0 ? rsqrtf((float)hist[t]) : 1.0f;
}

// ---- exclusive scan of dst-bucket counts -> bucket bases ----
__global__ __launch_bounds__(512) void k_bscan(const int* __restrict__ gcurD, int* __restrict__ bbase) {
    __shared__ int s[NB + 1];
    int t = threadIdx.x;
    if (t < NB) s[t] = min(gcurD[t], BCAP);
    __syncthreads();
    if (t == 0) {
        int run = 0;
        for (int b = 0; b < NB; b++) { int v = s[b]; s[b] = run; run += v; }
        s[NB] = run;
    }
    __syncthreads();
    if (t < NB) bbase[t] = s[t];
    if (t == 0) bbase[NB] = s[NB];
}

// ---- per-bucket counting sort by key (dstLow, srcSlice): emits csr_src sorted by
// (dst, slice), rp2[node*16+p] segment starts (entry 13..15 = node end), in_norm.
// hist stride 17 keeps per-thread serial bin walks bank-conflict-free.
__global__ __launch_bounds__(256) void k_bsort(const unsigned int* __restrict__ ebuf, const int* __restrict__ gcurD,
                                               const int* __restrict__ bbase, int* __restrict__ csr_src,
                                               int* __restrict__ rp2, float* __restrict__ in_norm) {
    __shared__ unsigned int st[BCAP];   // 20 KB staged edges
    __shared__ int perm[BCAP];          // 20 KB sorted srcs
    __shared__ int hist[256 * 17];      // 17.4 KB (node-major, stride 17)
    __shared__ int sa[256], sb[256];
    int b = blockIdx.x, t = threadIdx.x;
    int ne = min(gcurD[b], BCAP);
    const unsigned int* eb = ebuf + (size_t)b * BCAP;
    for (int i = t; i < 256 * 17; i += 256) hist[i] = 0;
    __syncthreads();
    for (int i = t; i < ne; i += 256) {
        unsigned int pk = eb[i];            // src<<8 | dstLow
        st[i] = pk;
        int key = (int)(pk & 255u) * 17 + (int)(pk >> (8 + SLICE_SHIFT));
        atomicAdd(&hist[key], 1);
    }
    __syncthreads();
    // per-node totals + block scan
    int tot = 0;
#pragma unroll
    for (int k = 0; k < NSLICE; k++) tot += hist[t * 17 + k];
    sa[t] = tot;
    __syncthreads();
    int* cur = sa; int* nxt = sb;
    for (int o = 1; o < 256; o <<= 1) {
        int v = cur[t] + (t >= o ? cur[t - o] : 0);
        nxt[t] = v;
        __syncthreads();
        int* tmp = cur; cur = nxt; nxt = tmp;
    }
    int nodeBase = cur[t] - tot;   // exclusive
    int gb = bbase[b];
    int node = b * 256 + t;
    if (node < N_NODES) {
        int run = gb + nodeBase;
#pragma unroll
        for (int k = 0; k < NSLICE; k++) {
            rp2[(size_t)node * 16 + k] = run;
            int c = hist[t * 17 + k];
            hist[t * 17 + k] = run - gb;   // bucket-relative cursor for perm
            run += c;
        }
        rp2[(size_t)node * 16 + 13] = run;
        rp2[(size_t)node * 16 + 14] = run;
        rp2[(size_t)node * 16 + 15] = run;
        in_norm[node] = tot > 0 ? rsqrtf((float)tot) : 1.0f;
    }
    __syncthreads();
    for (int i = t; i < ne; i += 256) {
        unsigned int pk = st[i];
        int key = (int)(pk & 255u) * 17 + (int)(pk >> (8 + SLICE_SHIFT));
        int pos = atomicAdd(&hist[key], 1);
        perm[pos] = (int)(pk >> 8);
    }
    __syncthreads();
    for (int i = t; i < ne; i += 256) csr_src[gb + i] = perm[i];
}

// ---- layer-1 aggregation: persistent, slice-major for L2 residency ----
// 8192 waves exactly resident (32/CU); wave owns nodes wid+8192k (k<13);
// outer loop over 13 src slices (2 MB of xb each) -> all resident waves touch
// the same 2 MB window together. Each edge reads a contiguous 256 B row.
__global__ __launch_bounds__(256, 8) void k_agg1(const unsigned short* __restrict__ xb,
                                                 const int* __restrict__ rp2, const int* __restrict__ csr,
                                                 const float* __restrict__ in_norm,
                                                 unsigned short* __restrict__ aggb) {
    int wave = __builtin_amdgcn_readfirstlane(threadIdx.x >> 6);
    int lane = threadIdx.x & 63;
    int wid = blockIdx.x * 4 + wave;
    int col = lane << 1;
    float aL[13], aH[13];
#pragma unroll
    for (int k = 0; k < 13; k++) { aL[k] = 0.f; aH[k] = 0.f; }
#pragma unroll 1
    for (int p = 0; p < NSLICE; p++) {
#pragma unroll
        for (int k = 0; k < 13; k++) {
            int d = wid + k * NWAVES;
            if (d < N_NODES) {
                int e0 = __builtin_amdgcn_readfirstlane(rp2[(size_t)d * 16 + p]);
                int e1 = __builtin_amdgcn_readfirstlane(rp2[(size_t)d * 16 + p + 1]);
#pragma unroll 1
                for (int e = e0; e < e1; e++) {
                    int s = __builtin_amdgcn_readfirstlane(csr[e]);
                    unsigned int v = *(const unsigned int*)(xb + (size_t)s * 128 + col);
                    aH[k] += __builtin_bit_cast(float, v & 0xffff0000u);
                    aL[k] += __builtin_bit_cast(float, v << 16);
                }
            }
        }
    }
#pragma unroll
    for (int k = 0; k < 13; k++) {
        int d = wid + k * NWAVES;
        if (d < N_NODES) {
            float w = in_norm[d];
            unsigned int pk = (unsigned int)f2bf(aL[k] * w) | ((unsigned int)f2bf(aH[k] * w) << 16);
            *(unsigned int*)(aggb + (size_t)d * 128 + col) = pk;
        }
    }
}

// ---- fused GEMM1+GEMM2 (unchanged from R7) ----
__global__ __launch_bounds__(256) void k_gemm12(const unsigned short* __restrict__ Ab,
                                                const unsigned short* __restrict__ Wp1,
                                                const unsigned short* __restrict__ Wp2,
                                                const float* __restrict__ bias1,
                                                const float* __restrict__ out_norm,
                                                float* __restrict__ z_out,
                                                unsigned short* __restrict__ tb) {
    __shared__ __align__(16) unsigned short lds1[16 * 128 * 8];   // 32 KB packed W1
    __shared__ __align__(16) unsigned short lds2[16 * 64 * 8];    // 16 KB packed W2
    __shared__ __align__(16) unsigned short zt[64 * 132];         // 16.5 KB zs tile
    {
        const uint4* s1 = (const uint4*)Wp1; uint4* d1 = (uint4*)lds1;
        for (int i = threadIdx.x; i < 2048; i += 256) d1[i] = s1[i];
        const uint4* s2 = (const uint4*)Wp2; uint4* d2 = (uint4*)lds2;
        for (int i = threadIdx.x; i < 1024; i += 256) d2[i] = s2[i];
    }
    __syncthreads();
    int wave = threadIdx.x >> 6, lane = threadIdx.x & 63;
    int base = (blockIdx.x * 4 + wave) * 16;
    if (base >= N_NODES) return;
    int m = lane & 15, q = lane >> 4;
    short8 a[4];
#pragma unroll
    for (int t = 0; t < 4; t++) a[t] = *(const short8*)(Ab + (size_t)(base + m) * 128 + t * 32 + q * 8);
    f32x4 acc[8];
#pragma unroll
    for (int c = 0; c < 8; c++) acc[c] = (f32x4)(0.f);
#pragma unroll
    for (int ct = 0; ct < 8; ct++) {
#pragma unroll
        for (int t = 0; t < 4; t++) {
            short8 b = *(const short8*)(lds1 + ((t * 4 + q) * 128 + ct * 16 + m) * 8);
            acc[ct] = __builtin_amdgcn_mfma_f32_16x16x32_bf16(a[t], b, acc[ct], 0, 0, 0);
        }
    }
    float onr[4];
#pragma unroll
    for (int i = 0; i < 4; i++) onr[i] = out_norm[base + q * 4 + i];
#pragma unroll
    for (int ct = 0; ct < 8; ct++) {
        int col = ct * 16 + m;
        float bv = bias1[col];
#pragma unroll
        for (int i = 0; i < 4; i++) {
            int row = base + q * 4 + i;
            float v = acc[ct][i] + bv;
            v = v > 0.f ? v : 0.f;
            z_out[(size_t)row * 128 + col] = v;
            zt[(wave * 16 + q * 4 + i) * 132 + col] = f2bf(v * onr[i]);
        }
    }
    // zt rows wave-private; intra-wave lgkmcnt suffices, no barrier.
    short8 a2[4];
#pragma unroll
    for (int t = 0; t < 4; t++) a2[t] = *(const short8*)(zt + (wave * 16 + m) * 132 + t * 32 + q * 8);
    f32x4 acc2[4];
#pragma unroll
    for (int c = 0; c < 4; c++) acc2[c] = (f32x4)(0.f);
#pragma unroll
    for (int ct = 0; ct < 4; ct++) {
#pragma unroll
        for (int t = 0; t < 4; t++) {
            short8 b = *(const short8*)(lds2 + ((t * 4 + q) * 64 + ct * 16 + m) * 8);
            acc2[ct] = __builtin_amdgcn_mfma_f32_16x16x32_bf16(a2[t], b, acc2[ct], 0, 0, 0);
        }
    }
#pragma unroll
    for (int ct = 0; ct < 4; ct++) {
        int col = ct * 16 + m;
#pragma unroll
        for (int i = 0; i < 4; i++) {
            int row = base + q * 4 + i;
            tb[(size_t)row * 64 + col] = f2bf(acc2[ct][i]);
        }
    }
}

// ---- layer-2 aggregation: persistent slice-major (tb slices 1 MB); 128 B/edge ----
__global__ __launch_bounds__(256, 8) void k_agg2(const unsigned short* __restrict__ tb,
                                                 const int* __restrict__ rp2, const int* __restrict__ csr,
                                                 const float* __restrict__ in_norm, const float* __restrict__ b2,
                                                 float* __restrict__ out_h2) {
    int wave = __builtin_amdgcn_readfirstlane(threadIdx.x >> 6);
    int lane = threadIdx.x & 63;
    int wid = blockIdx.x * 4 + wave;
    float bv = b2[lane];
    float acc[13];
#pragma unroll
    for (int k = 0; k < 13; k++) acc[k] = 0.f;
#pragma unroll 1
    for (int p = 0; p < NSLICE; p++) {
#pragma unroll
        for (int k = 0; k < 13; k++) {
            int d = wid + k * NWAVES;
            if (d < N_NODES) {
                int e0 = __builtin_amdgcn_readfirstlane(rp2[(size_t)d * 16 + p]);
                int e1 = __builtin_amdgcn_readfirstlane(rp2[(size_t)d * 16 + p + 1]);
#pragma unroll 1
                for (int e = e0; e < e1; e++) {
                    int s = __builtin_amdgcn_readfirstlane(csr[e]);
                    unsigned int u = (unsigned int)tb[(size_t)s * 64 + lane];
                    acc[k] += __builtin_bit_cast(float, u << 16);
                }
            }
        }
    }
#pragma unroll
    for (int k = 0; k < 13; k++) {
        int d = wid + k * NWAVES;
        if (d < N_NODES) out_h2[(size_t)d * 64 + lane] = acc[k] * in_norm[d] + bv;
    }
}

extern "C" void kernel_launch(void* const* d_in, const int* in_sizes, int n_in,
                              void* d_out, int out_size, void* d_ws, size_t ws_size,
                              hipStream_t stream) {
    const float* x   = (const float*)d_in[0];
    const int*   src = (const int*)d_in[1];
    const int*   dst = (const int*)d_in[2];
    const float* W1  = (const float*)d_in[3];
    const float* b1  = (const float*)d_in[4];
    const float* W2  = (const float*)d_in[5];
    const float* b2  = (const float*)d_in[6];
    float* out_h2 = (float*)d_out;                     // [N,64]
    float* out_z  = (float*)d_out + N_NODES * 64;      // [N,128]

    char* ws = (char*)d_ws;
    size_t off = 0;
    auto alloc = [&](size_t bytes) -> char* {
        char* p = ws + off;
        off = (off + bytes + 255) & ~(size_t)255;
        return p;
    };
    int* gcurD    = (int*)alloc(NB * 4);
    int* gcurS    = (int*)alloc(NB * 4);
    int* bbase    = (int*)alloc((NB + 1) * 4);
    int* rp2      = (int*)alloc((size_t)N_NODES * 16 * 4);   // 6.4 MB segment table
    float* out_norm = (float*)alloc(N_NODES * 4);
    float* in_norm  = (float*)alloc(N_NODES * 4);
    unsigned int* ebuf = (unsigned int*)alloc((size_t)NB * BCAP * 4);        // 8.0 MB
    unsigned char* ebufS = (unsigned char*)alloc((size_t)NB * BCAP);         // 2.0 MB
    int* csr_src  = (int*)alloc((size_t)N_EDGES * 4);
    unsigned short* Wp1 = (unsigned short*)alloc(2048 * 8 * 2);
    unsigned short* Wp2 = (unsigned short*)alloc(1024 * 8 * 2);
    unsigned short* xb    = (unsigned short*)alloc((size_t)N_NODES * 128 * 2);
    unsigned short* agg1b = (unsigned short*)alloc((size_t)N_NODES * 128 * 2);
    unsigned short* tb    = (unsigned short*)alloc((size_t)N_NODES * 64 * 2);  // bf16 t
    (void)ws_size; (void)in_sizes; (void)n_in; (void)out_size;

    hipMemsetAsync(gcurD, 0, NB * 4, stream);
    hipMemsetAsync(gcurS, 0, NB * 4, stream);

    const int GD_AGG = NWAVES / 4;              // 2048 persistent blocks
    const int GD_GEMM = (N_NODES / 16 + 3) / 4; // 1563

    k_part<<<PART_BLOCKS, 256, 0, stream>>>(src, dst, gcurD, gcurS, ebuf, ebufS);
    k_bhist<<<NB, 256, 0, stream>>>(ebufS, gcurS, out_norm);
    k_bscan<<<1, 512, 0, stream>>>(gcurD, bbase);
    k_bsort<<<NB, 256, 0, stream>>>(ebuf, gcurD, bbase, csr_src, rp2, in_norm);
    k_xb<<<N_NODES * 32 / 256, 256, 0, stream>>>(x, out_norm, xb);
    k_pack_w<<<12, 256, 0, stream>>>(W1, W2, Wp1, Wp2);
    k_agg1<<<GD_AGG, 256, 0, stream>>>(xb, rp2, csr_src, in_norm, agg1b);
    k_gemm12<<<GD_GEMM, 256, 0, stream>>>(agg1b, Wp1, Wp2, b1, out_norm, out_z, tb);
    k_agg2<<<GD_AGG, 256, 0, stream>>>(tb, rp2, csr_src, in_norm, b2, out_h2);
}

// Round 9
// 323.928 us; speedup vs baseline: 1.5033x; 1.5033x over previous
//
#include <hip/hip_runtime.h>

#define N_NODES 100000
#define N_EDGES 1600000
#define NB 391          // coarse buckets of 256 nodes
#define BCAP 5120       // per-bucket capacity (expected 4096, 16-sigma headroom)
#define PART_BLOCKS 250
#define EPB 6400        // edges per partition block (250*6400 = 1.6M exact)

typedef __attribute__((ext_vector_type(8))) short short8;   // 8 bf16 (4 VGPR) MFMA frag
typedef __attribute__((ext_vector_type(4))) float f32x4;    // MFMA accumulator

__device__ inline unsigned short f2bf(float f) {
    unsigned int u = __builtin_bit_cast(unsigned int, f);
    u += 0x7fffu + ((u >> 16) & 1u);   // round-to-nearest-even
    return (unsigned short)(u >> 16);
}
__device__ inline float bf2f(unsigned short h) {
    unsigned int u = ((unsigned int)h) << 16;
    return __builtin_bit_cast(float, u);
}

// ---- xb = bf16(x * out_norm[row]) ----
__global__ __launch_bounds__(256) void k_xb(const float* __restrict__ x, const float* __restrict__ out_norm,
                                            unsigned short* __restrict__ xb) {
    int tid = blockIdx.x * 256 + threadIdx.x;   // grid exactly N*32
    int row = tid >> 5;
    float4 v = ((const float4*)x)[tid];
    float w = out_norm[row];
    unsigned int lo = (unsigned int)f2bf(v.x * w) | ((unsigned int)f2bf(v.y * w) << 16);
    unsigned int hi = (unsigned int)f2bf(v.z * w) | ((unsigned int)f2bf(v.w * w) << 16);
    ((uint2*)xb)[tid] = make_uint2(lo, hi);
}

// ---- pack W1/W2 (f32) into bf16 B-fragment layout: entry (kq, c) = W[kq*8+j][c], j=0..7 ----
__global__ __launch_bounds__(256) void k_pack_w(const float* __restrict__ W1, const float* __restrict__ W2,
                                                unsigned short* __restrict__ Wp1, unsigned short* __restrict__ Wp2) {
    int i = blockIdx.x * 256 + threadIdx.x;   // 3072 total
    if (i < 2048) {                           // W1: 16 kq x 128 c
        int kq = i >> 7, c = i & 127;
#pragma unroll
        for (int j = 0; j < 8; j++) Wp1[i * 8 + j] = f2bf(W1[(kq * 8 + j) * 128 + c]);
    } else if (i < 3072) {                    // W2: 16 kq x 64 c
        int i2 = i - 2048;
        int kq = i2 >> 6, c = i2 & 63;
#pragma unroll
        for (int j = 0; j < 8; j++) Wp2[i2 * 8 + j] = f2bf(W2[(kq * 8 + j) * 64 + c]);
    }
}

// ---- partition: dst-keyed buckets (full edge) + src-keyed buckets (1 byte) ----
__global__ __launch_bounds__(256) void k_part(const int* __restrict__ src, const int* __restrict__ dst,
                                              int* __restrict__ gcurD, int* __restrict__ gcurS,
                                              unsigned int* __restrict__ ebuf,
                                              unsigned char* __restrict__ ebufS) {
    __shared__ int histD[NB], gbaseD[NB];
    __shared__ int histS[NB], gbaseS[NB];
    for (int i = threadIdx.x; i < NB; i += 256) { histD[i] = 0; histS[i] = 0; }
    __syncthreads();
    int base = blockIdx.x * EPB;
    for (int i = threadIdx.x; i < EPB; i += 256) {
        int d = dst[base + i], s = src[base + i];
        atomicAdd(&histD[d >> 8], 1);
        atomicAdd(&histS[s >> 8], 1);
    }
    __syncthreads();
    for (int i = threadIdx.x; i < NB; i += 256) {
        gbaseD[i] = atomicAdd(&gcurD[i], histD[i]);
        gbaseS[i] = atomicAdd(&gcurS[i], histS[i]);
        histD[i] = 0;                          // reuse as local run cursors
        histS[i] = 0;
    }
    __syncthreads();
    for (int i = threadIdx.x; i < EPB; i += 256) {
        int d = dst[base + i], s = src[base + i];
        int bd = d >> 8;
        int r = atomicAdd(&histD[bd], 1);
        int pos = gbaseD[bd] + r;
        if (pos < BCAP) ebuf[(size_t)bd * BCAP + pos] = ((unsigned int)s << 8) | (unsigned int)(d & 255);
        int bs = s >> 8;
        int r2 = atomicAdd(&histS[bs], 1);
        int pos2 = gbaseS[bs] + r2;
        if (pos2 < BCAP) ebufS[(size_t)bs * BCAP + pos2] = (unsigned char)(s & 255);
    }
}

// ---- fused: blocks 0..NB-1 do per-bucket out-degree histogram -> out_norm;
//      block NB does the exclusive scan of dst-bucket counts -> bbase, row_ptr[N]=E ----
__global__ __launch_bounds__(256) void k_bhist_scan(const unsigned char* __restrict__ ebufS,
                                                    const int* __restrict__ gcurS,
                                                    float* __restrict__ out_norm,
                                                    const int* __restrict__ gcurD,
                                                    int* __restrict__ bbase, int* __restrict__ row_ptr) {
    int t = threadIdx.x;
    if (blockIdx.x < NB) {
        __shared__ int hist[256];
        int b = blockIdx.x;
        hist[t] = 0;
        __syncthreads();
        int ne = min(gcurS[b], BCAP);
        const unsigned char* eb = ebufS + (size_t)b * BCAP;
        for (int i = t; i < ne; i += 256) atomicAdd(&hist[eb[i]], 1);
        __syncthreads();
        int node = b * 256 + t;
        if (node < N_NODES) out_norm[node] = hist[t] > 0 ? rsqrtf((float)hist[t]) : 1.0f;
    } else {
        __shared__ int s[NB + 1];
        for (int i = t; i < NB; i += 256) s[i] = min(gcurD[i], BCAP);
        __syncthreads();
        if (t == 0) {
            int run = 0;
            for (int b = 0; b < NB; b++) { int v = s[b]; s[b] = run; run += v; }
            s[NB] = run;
        }
        __syncthreads();
        for (int i = t; i < NB + 1; i += 256) bbase[i] = s[i];
        if (t == 0) row_ptr[N_NODES] = s[NB];
    }
}

// ---- per-bucket counting sort in LDS: emits coalesced csr_src, row_ptr, in_norm ----
__global__ __launch_bounds__(256) void k_bsort(const unsigned int* __restrict__ ebuf, const int* __restrict__ gcurD,
                                               const int* __restrict__ bbase, int* __restrict__ csr_src,
                                               int* __restrict__ row_ptr, float* __restrict__ in_norm) {
    __shared__ unsigned int st[BCAP];   // 20 KB staged edges
    __shared__ int perm[BCAP];          // 20 KB sorted srcs
    __shared__ int hist[256], cursor[256], sa[256], sb[256];
    int b = blockIdx.x, t = threadIdx.x;
    int ne = min(gcurD[b], BCAP);
    const unsigned int* eb = ebuf + (size_t)b * BCAP;
    hist[t] = 0;
    __syncthreads();
    for (int i = t; i < ne; i += 256) {
        unsigned int pk = eb[i];
        st[i] = pk;
        atomicAdd(&hist[pk & 255u], 1);
    }
    __syncthreads();
    sa[t] = hist[t];
    __syncthreads();
    int* cur = sa; int* nxt = sb;
    for (int o = 1; o < 256; o <<= 1) {
        int v = cur[t] + (t >= o ? cur[t - o] : 0);
        nxt[t] = v;
        __syncthreads();
        int* tmp = cur; cur = nxt; nxt = tmp;
    }
    int ex = cur[t] - hist[t];   // exclusive
    cursor[t] = ex;
    int node = b * 256 + t;
    if (node < N_NODES) {
        row_ptr[node] = bbase[b] + ex;
        in_norm[node] = hist[t] > 0 ? rsqrtf((float)hist[t]) : 1.0f;
    }
    __syncthreads();
    for (int i = t; i < ne; i += 256) {
        unsigned int pk = st[i];
        int pos = atomicAdd(&cursor[pk & 255u], 1);
        perm[pos] = (int)(pk >> 8);
    }
    __syncthreads();
    int gb = bbase[b];
    for (int i = t; i < ne; i += 256) csr_src[gb + i] = perm[i];
}

// ---- layer-1 aggregation: wave per dst node, 128 bf16 cols (2/lane), f32 accum ----
// 8-deep unrolled gather; 256 B contiguous per edge-instruction. This is the
// local floor: FETCH ~182 MB ~= 8 XCDs x 25.6 MB table (compulsory per-XCD
// fill); 16-deep (R7) and slice-major (R8) both regressed.
__global__ __launch_bounds__(256) void k_agg1(const unsigned short* __restrict__ xb,
                                              const int* __restrict__ row_ptr, const int* __restrict__ csr,
                                              const float* __restrict__ in_norm,
                                              unsigned short* __restrict__ aggb) {
    int wave = threadIdx.x >> 6, lane = threadIdx.x & 63;
    int d = blockIdx.x * 4 + wave;
    if (d >= N_NODES) return;
    int e0 = __builtin_amdgcn_readfirstlane(row_ptr[d]);
    int e1 = __builtin_amdgcn_readfirstlane(row_ptr[d + 1]);
    int col = lane << 1;
    float accL[8], accH[8];
#pragma unroll
    for (int j = 0; j < 8; j++) { accL[j] = 0.f; accH[j] = 0.f; }
    int e = e0;
    for (; e + 8 <= e1; e += 8) {
        int sI[8];
#pragma unroll
        for (int j = 0; j < 8; j++) sI[j] = __builtin_amdgcn_readfirstlane(csr[e + j]);
        unsigned int v[8];
#pragma unroll
        for (int j = 0; j < 8; j++) v[j] = *(const unsigned int*)(xb + (size_t)sI[j] * 128 + col);
#pragma unroll
        for (int j = 0; j < 8; j++) {
            accL[j] += bf2f((unsigned short)(v[j] & 0xffffu));
            accH[j] += bf2f((unsigned short)(v[j] >> 16));
        }
    }
    for (; e < e1; e++) {
        int s = __builtin_amdgcn_readfirstlane(csr[e]);
        unsigned int v = *(const unsigned int*)(xb + (size_t)s * 128 + col);
        accL[0] += bf2f((unsigned short)(v & 0xffffu));
        accH[0] += bf2f((unsigned short)(v >> 16));
    }
    float a0 = 0.f, a1 = 0.f;
#pragma unroll
    for (int j = 0; j < 8; j++) { a0 += accL[j]; a1 += accH[j]; }
    float w = in_norm[d];
    unsigned int pk = (unsigned int)f2bf(a0 * w) | ((unsigned int)f2bf(a1 * w) << 16);
    *(unsigned int*)(aggb + (size_t)d * 128 + col) = pk;
}

// ---- fused GEMM1+GEMM2: z = relu(agg1b@W1+b1) -> z_out; zs=bf16(z*out_norm)
// via wave-private LDS tile (stride 132: conflict-free both directions); tb=bf16(zs@W2).
__global__ __launch_bounds__(256) void k_gemm12(const unsigned short* __restrict__ Ab,
                                                const unsigned short* __restrict__ Wp1,
                                                const unsigned short* __restrict__ Wp2,
                                                const float* __restrict__ bias1,
                                                const float* __restrict__ out_norm,
                                                float* __restrict__ z_out,
                                                unsigned short* __restrict__ tb) {
    __shared__ __align__(16) unsigned short lds1[16 * 128 * 8];   // 32 KB packed W1
    __shared__ __align__(16) unsigned short lds2[16 * 64 * 8];    // 16 KB packed W2
    __shared__ __align__(16) unsigned short zt[64 * 132];         // 16.5 KB zs tile
    {
        const uint4* s1 = (const uint4*)Wp1; uint4* d1 = (uint4*)lds1;
        for (int i = threadIdx.x; i < 2048; i += 256) d1[i] = s1[i];
        const uint4* s2 = (const uint4*)Wp2; uint4* d2 = (uint4*)lds2;
        for (int i = threadIdx.x; i < 1024; i += 256) d2[i] = s2[i];
    }
    __syncthreads();
    int wave = threadIdx.x >> 6, lane = threadIdx.x & 63;
    int base = (blockIdx.x * 4 + wave) * 16;
    if (base >= N_NODES) return;
    int m = lane & 15, q = lane >> 4;
    short8 a[4];
#pragma unroll
    for (int t = 0; t < 4; t++) a[t] = *(const short8*)(Ab + (size_t)(base + m) * 128 + t * 32 + q * 8);
    f32x4 acc[8];
#pragma unroll
    for (int c = 0; c < 8; c++) acc[c] = (f32x4)(0.f);
#pragma unroll
    for (int ct = 0; ct < 8; ct++) {
#pragma unroll
        for (int t = 0; t < 4; t++) {
            short8 b = *(const short8*)(lds1 + ((t * 4 + q) * 128 + ct * 16 + m) * 8);
            acc[ct] = __builtin_amdgcn_mfma_f32_16x16x32_bf16(a[t], b, acc[ct], 0, 0, 0);
        }
    }
    float onr[4];
#pragma unroll
    for (int i = 0; i < 4; i++) onr[i] = out_norm[base + q * 4 + i];
#pragma unroll
    for (int ct = 0; ct < 8; ct++) {
        int col = ct * 16 + m;
        float bv = bias1[col];
#pragma unroll
        for (int i = 0; i < 4; i++) {
            int row = base + q * 4 + i;
            float v = acc[ct][i] + bv;
            v = v > 0.f ? v : 0.f;
            z_out[(size_t)row * 128 + col] = v;
            zt[(wave * 16 + q * 4 + i) * 132 + col] = f2bf(v * onr[i]);
        }
    }
    // zt rows wave-private; intra-wave lgkmcnt suffices, no barrier.
    short8 a2[4];
#pragma unroll
    for (int t = 0; t < 4; t++) a2[t] = *(const short8*)(zt + (wave * 16 + m) * 132 + t * 32 + q * 8);
    f32x4 acc2[4];
#pragma unroll
    for (int c = 0; c < 4; c++) acc2[c] = (f32x4)(0.f);
#pragma unroll
    for (int ct = 0; ct < 4; ct++) {
#pragma unroll
        for (int t = 0; t < 4; t++) {
            short8 b = *(const short8*)(lds2 + ((t * 4 + q) * 64 + ct * 16 + m) * 8);
            acc2[ct] = __builtin_amdgcn_mfma_f32_16x16x32_bf16(a2[t], b, acc2[ct], 0, 0, 0);
        }
    }
#pragma unroll
    for (int ct = 0; ct < 4; ct++) {
        int col = ct * 16 + m;
#pragma unroll
        for (int i = 0; i < 4; i++) {
            int row = base + q * 4 + i;
            tb[(size_t)row * 64 + col] = f2bf(acc2[ct][i]);
        }
    }
}

// ---- layer-2 aggregation: wave per dst node, 64 bf16 cols (1/lane), f32 accum ----
// 8-deep unroll; 128 B contiguous per edge-instruction.
__global__ __launch_bounds__(256) void k_agg2(const unsigned short* __restrict__ tb,
                                              const int* __restrict__ row_ptr, const int* __restrict__ csr,
                                              const float* __restrict__ in_norm, const float* __restrict__ b2,
                                              float* __restrict__ out_h2) {
    int wave = threadIdx.x >> 6, lane = threadIdx.x & 63;
    int d = blockIdx.x * 4 + wave;
    if (d >= N_NODES) return;
    int e0 = __builtin_amdgcn_readfirstlane(row_ptr[d]);
    int e1 = __builtin_amdgcn_readfirstlane(row_ptr[d + 1]);
    float acc[8];
#pragma unroll
    for (int j = 0; j < 8; j++) acc[j] = 0.f;
    int e = e0;
    for (; e + 8 <= e1; e += 8) {
        int sI[8];
#pragma unroll
        for (int j = 0; j < 8; j++) sI[j] = __builtin_amdgcn_readfirstlane(csr[e + j]);
        unsigned short v[8];
#pragma unroll
        for (int j = 0; j < 8; j++) v[j] = tb[(size_t)sI[j] * 64 + lane];
#pragma unroll
        for (int j = 0; j < 8; j++) acc[j] += bf2f(v[j]);
    }
    for (; e < e1; e++) {
        int s = __builtin_amdgcn_readfirstlane(csr[e]);
        acc[0] += bf2f(tb[(size_t)s * 64 + lane]);
    }
    float a = 0.f;
#pragma unroll
    for (int j = 0; j < 8; j++) a += acc[j];
    out_h2[(size_t)d * 64 + lane] = a * in_norm[d] + b2[lane];
}

extern "C" void kernel_launch(void* const* d_in, const int* in_sizes, int n_in,
                              void* d_out, int out_size, void* d_ws, size_t ws_size,
                              hipStream_t stream) {
    const float* x   = (const float*)d_in[0];
    const int*   src = (const int*)d_in[1];
    const int*   dst = (const int*)d_in[2];
    const float* W1  = (const float*)d_in[3];
    const float* b1  = (const float*)d_in[4];
    const float* W2  = (const float*)d_in[5];
    const float* b2  = (const float*)d_in[6];
    float* out_h2 = (float*)d_out;                     // [N,64]
    float* out_z  = (float*)d_out + N_NODES * 64;      // [N,128]

    char* ws = (char*)d_ws;
    size_t off = 0;
    auto alloc = [&](size_t bytes) -> char* {
        char* p = ws + off;
        off = (off + bytes + 255) & ~(size_t)255;
        return p;
    };
    int* gcurD    = (int*)alloc(NB * 4);
    int* gcurS    = (int*)alloc(NB * 4);
    int* bbase    = (int*)alloc((NB + 1) * 4);
    int* row_ptr  = (int*)alloc((N_NODES + 1) * 4);
    float* out_norm = (float*)alloc(N_NODES * 4);
    float* in_norm  = (float*)alloc(N_NODES * 4);
    unsigned int* ebuf = (unsigned int*)alloc((size_t)NB * BCAP * 4);        // 8.0 MB
    unsigned char* ebufS = (unsigned char*)alloc((size_t)NB * BCAP);         // 2.0 MB
    int* csr_src  = (int*)alloc((size_t)N_EDGES * 4);
    unsigned short* Wp1 = (unsigned short*)alloc(2048 * 8 * 2);
    unsigned short* Wp2 = (unsigned short*)alloc(1024 * 8 * 2);
    unsigned short* xb    = (unsigned short*)alloc((size_t)N_NODES * 128 * 2);
    unsigned short* agg1b = (unsigned short*)alloc((size_t)N_NODES * 128 * 2);
    unsigned short* tb    = (unsigned short*)alloc((size_t)N_NODES * 64 * 2);  // bf16 t
    (void)ws_size; (void)in_sizes; (void)n_in; (void)out_size;

    hipMemsetAsync(gcurD, 0, NB * 4, stream);
    hipMemsetAsync(gcurS, 0, NB * 4, stream);

    const int GD_AGG = (N_NODES + 3) / 4;       // 25000
    const int GD_GEMM = (N_NODES / 16 + 3) / 4; // 1563

    k_part<<<PART_BLOCKS, 256, 0, stream>>>(src, dst, gcurD, gcurS, ebuf, ebufS);
    k_bhist_scan<<<NB + 1, 256, 0, stream>>>(ebufS, gcurS, out_norm, gcurD, bbase, row_ptr);
    k_bsort<<<NB, 256, 0, stream>>>(ebuf, gcurD, bbase, csr_src, row_ptr, in_norm);
    k_xb<<<N_NODES * 32 / 256, 256, 0, stream>>>(x, out_norm, xb);
    k_pack_w<<<12, 256, 0, stream>>>(W1, W2, Wp1, Wp2);
    k_agg1<<<GD_AGG, 256, 0, stream>>>(xb, row_ptr, csr_src, in_norm, agg1b);
    k_gemm12<<<GD_GEMM, 256, 0, stream>>>(agg1b, Wp1, Wp2, b1, out_norm, out_z, tb);
    k_agg2<<<GD_AGG, 256, 0, stream>>>(tb, row_ptr, csr_src, in_norm, b2, out_h2);
}

// Round 10
// 314.347 us; speedup vs baseline: 1.5491x; 1.0305x over previous
//
#include <hip/hip_runtime.h>

#define N_NODES 100000
#define N_EDGES 1600000
#define NB 391          // coarse buckets of 256 nodes
#define BCAP 5120       // per-bucket capacity (expected 4096, 16-sigma headroom)
#define PART_BLOCKS 250
#define EPB 6400        // edges per partition block (250*6400 = 1.6M exact)

typedef __attribute__((ext_vector_type(8))) short short8;   // 8 bf16 (4 VGPR) MFMA frag
typedef __attribute__((ext_vector_type(4))) float f32x4;    // MFMA accumulator

__device__ inline unsigned short f2bf(float f) {
    unsigned int u = __builtin_bit_cast(unsigned int, f);
    u += 0x7fffu + ((u >> 16) & 1u);   // round-to-nearest-even
    return (unsigned short)(u >> 16);
}
__device__ inline float bf2f(unsigned short h) {
    unsigned int u = ((unsigned int)h) << 16;
    return __builtin_bit_cast(float, u);
}

// ---- partition (blocks 0..249): dst-keyed buckets (full edge) + src-keyed (1 byte);
//      blocks 250..261: pack W1/W2 into bf16 B-fragment layout (independent work,
//      merged here to kill a launch + fill idle CUs) ----
__global__ __launch_bounds__(256) void k_part(const int* __restrict__ src, const int* __restrict__ dst,
                                              int* __restrict__ gcurD, int* __restrict__ gcurS,
                                              unsigned int* __restrict__ ebuf,
                                              unsigned char* __restrict__ ebufS,
                                              const float* __restrict__ W1, const float* __restrict__ W2,
                                              unsigned short* __restrict__ Wp1, unsigned short* __restrict__ Wp2) {
    if (blockIdx.x >= PART_BLOCKS) {          // ---- pack_w blocks ----
        int i = (blockIdx.x - PART_BLOCKS) * 256 + threadIdx.x;   // 3072 total
        if (i < 2048) {                       // W1: 16 kq x 128 c
            int kq = i >> 7, c = i & 127;
#pragma unroll
            for (int j = 0; j < 8; j++) Wp1[i * 8 + j] = f2bf(W1[(kq * 8 + j) * 128 + c]);
        } else if (i < 3072) {                // W2: 16 kq x 64 c
            int i2 = i - 2048;
            int kq = i2 >> 6, c = i2 & 63;
#pragma unroll
            for (int j = 0; j < 8; j++) Wp2[i2 * 8 + j] = f2bf(W2[(kq * 8 + j) * 64 + c]);
        }
        return;
    }
    __shared__ int histD[NB], gbaseD[NB];
    __shared__ int histS[NB], gbaseS[NB];
    for (int i = threadIdx.x; i < NB; i += 256) { histD[i] = 0; histS[i] = 0; }
    __syncthreads();
    int base = blockIdx.x * EPB;
    for (int i = threadIdx.x; i < EPB; i += 256) {
        int d = dst[base + i], s = src[base + i];
        atomicAdd(&histD[d >> 8], 1);
        atomicAdd(&histS[s >> 8], 1);
    }
    __syncthreads();
    for (int i = threadIdx.x; i < NB; i += 256) {
        gbaseD[i] = atomicAdd(&gcurD[i], histD[i]);
        gbaseS[i] = atomicAdd(&gcurS[i], histS[i]);
        histD[i] = 0;                          // reuse as local run cursors
        histS[i] = 0;
    }
    __syncthreads();
    for (int i = threadIdx.x; i < EPB; i += 256) {
        int d = dst[base + i], s = src[base + i];
        int bd = d >> 8;
        int r = atomicAdd(&histD[bd], 1);
        int pos = gbaseD[bd] + r;
        if (pos < BCAP) ebuf[(size_t)bd * BCAP + pos] = ((unsigned int)s << 8) | (unsigned int)(d & 255);
        int bs = s >> 8;
        int r2 = atomicAdd(&histS[bs], 1);
        int pos2 = gbaseS[bs] + r2;
        if (pos2 < BCAP) ebufS[(size_t)bs * BCAP + pos2] = (unsigned char)(s & 255);
    }
}

// ---- fused: blocks 0..NB-1 do per-bucket out-degree histogram -> out_norm;
//      block NB does the exclusive scan of dst-bucket counts -> bbase, row_ptr[N]=E ----
__global__ __launch_bounds__(256) void k_bhist_scan(const unsigned char* __restrict__ ebufS,
                                                    const int* __restrict__ gcurS,
                                                    float* __restrict__ out_norm,
                                                    const int* __restrict__ gcurD,
                                                    int* __restrict__ bbase, int* __restrict__ row_ptr) {
    int t = threadIdx.x;
    if (blockIdx.x < NB) {
        __shared__ int hist[256];
        int b = blockIdx.x;
        hist[t] = 0;
        __syncthreads();
        int ne = min(gcurS[b], BCAP);
        const unsigned char* eb = ebufS + (size_t)b * BCAP;
        for (int i = t; i < ne; i += 256) atomicAdd(&hist[eb[i]], 1);
        __syncthreads();
        int node = b * 256 + t;
        if (node < N_NODES) out_norm[node] = hist[t] > 0 ? rsqrtf((float)hist[t]) : 1.0f;
    } else {
        __shared__ int s[NB + 1];
        for (int i = t; i < NB; i += 256) s[i] = min(gcurD[i], BCAP);
        __syncthreads();
        if (t == 0) {
            int run = 0;
            for (int b = 0; b < NB; b++) { int v = s[b]; s[b] = run; run += v; }
            s[NB] = run;
        }
        __syncthreads();
        for (int i = t; i < NB + 1; i += 256) bbase[i] = s[i];
        if (t == 0) row_ptr[N_NODES] = s[NB];
    }
}

// ---- merged launch: blocks 0..NB-1 = per-bucket counting sort (391 blocks alone
// under-fill 256 CUs); blocks NB.. = xb = bf16(x*out_norm) streaming scale (12500
// blocks) — both depend only on k_bhist_scan, so co-executing them recovers the
// dead parallelism of the sort stage and kills a launch barrier. ----
__global__ __launch_bounds__(256) void k_bsort_xb(const unsigned int* __restrict__ ebuf, const int* __restrict__ gcurD,
                                                  const int* __restrict__ bbase, int* __restrict__ csr_src,
                                                  int* __restrict__ row_ptr, float* __restrict__ in_norm,
                                                  const float* __restrict__ x, const float* __restrict__ out_norm,
                                                  unsigned short* __restrict__ xb) {
    __shared__ unsigned int st[BCAP];   // 20 KB staged edges
    __shared__ int perm[BCAP];          // 20 KB sorted srcs
    __shared__ int hist[256], cursor[256], sa[256], sb[256];
    int t = threadIdx.x;
    if (blockIdx.x >= NB) {             // ---- xb blocks ----
        int tid = (blockIdx.x - NB) * 256 + t;   // 12500 blocks x 256 = N*32 exact
        int row = tid >> 5;
        float4 v = ((const float4*)x)[tid];
        float w = out_norm[row];
        unsigned int lo = (unsigned int)f2bf(v.x * w) | ((unsigned int)f2bf(v.y * w) << 16);
        unsigned int hi = (unsigned int)f2bf(v.z * w) | ((unsigned int)f2bf(v.w * w) << 16);
        ((uint2*)xb)[tid] = make_uint2(lo, hi);
        return;
    }
    int b = blockIdx.x;
    int ne = min(gcurD[b], BCAP);
    const unsigned int* eb = ebuf + (size_t)b * BCAP;
    hist[t] = 0;
    __syncthreads();
    for (int i = t; i < ne; i += 256) {
        unsigned int pk = eb[i];
        st[i] = pk;
        atomicAdd(&hist[pk & 255u], 1);
    }
    __syncthreads();
    sa[t] = hist[t];
    __syncthreads();
    int* cur = sa; int* nxt = sb;
    for (int o = 1; o < 256; o <<= 1) {
        int v = cur[t] + (t >= o ? cur[t - o] : 0);
        nxt[t] = v;
        __syncthreads();
        int* tmp = cur; cur = nxt; nxt = tmp;
    }
    int ex = cur[t] - hist[t];   // exclusive
    cursor[t] = ex;
    int node = b * 256 + t;
    if (node < N_NODES) {
        row_ptr[node] = bbase[b] + ex;
        in_norm[node] = hist[t] > 0 ? rsqrtf((float)hist[t]) : 1.0f;
    }
    __syncthreads();
    for (int i = t; i < ne; i += 256) {
        unsigned int pk = st[i];
        int pos = atomicAdd(&cursor[pk & 255u], 1);
        perm[pos] = (int)(pk >> 8);
    }
    __syncthreads();
    int gb = bbase[b];
    for (int i = t; i < ne; i += 256) csr_src[gb + i] = perm[i];
}

// ---- layer-1 aggregation: wave per dst node, 128 bf16 cols (2/lane), f32 accum ----
// 8-deep unrolled gather; 256 B contiguous per edge-instruction. Near its floor:
// FETCH ~182 MB ~= 8 XCDs x 22.8 MB compulsory table fill at ~3.5 TB/s random-fill
// ceiling; 16-deep (R7) and slice-major (R8) both regressed. DO NOT TOUCH.
__global__ __launch_bounds__(256) void k_agg1(const unsigned short* __restrict__ xb,
                                              const int* __restrict__ row_ptr, const int* __restrict__ csr,
                                              const float* __restrict__ in_norm,
                                              unsigned short* __restrict__ aggb) {
    int wave = threadIdx.x >> 6, lane = threadIdx.x & 63;
    int d = blockIdx.x * 4 + wave;
    if (d >= N_NODES) return;
    int e0 = __builtin_amdgcn_readfirstlane(row_ptr[d]);
    int e1 = __builtin_amdgcn_readfirstlane(row_ptr[d + 1]);
    int col = lane << 1;
    float accL[8], accH[8];
#pragma unroll
    for (int j = 0; j < 8; j++) { accL[j] = 0.f; accH[j] = 0.f; }
    int e = e0;
    for (; e + 8 <= e1; e += 8) {
        int sI[8];
#pragma unroll
        for (int j = 0; j < 8; j++) sI[j] = __builtin_amdgcn_readfirstlane(csr[e + j]);
        unsigned int v[8];
#pragma unroll
        for (int j = 0; j < 8; j++) v[j] = *(const unsigned int*)(xb + (size_t)sI[j] * 128 + col);
#pragma unroll
        for (int j = 0; j < 8; j++) {
            accL[j] += bf2f((unsigned short)(v[j] & 0xffffu));
            accH[j] += bf2f((unsigned short)(v[j] >> 16));
        }
    }
    for (; e < e1; e++) {
        int s = __builtin_amdgcn_readfirstlane(csr[e]);
        unsigned int v = *(const unsigned int*)(xb + (size_t)s * 128 + col);
        accL[0] += bf2f((unsigned short)(v & 0xffffu));
        accH[0] += bf2f((unsigned short)(v >> 16));
    }
    float a0 = 0.f, a1 = 0.f;
#pragma unroll
    for (int j = 0; j < 8; j++) { a0 += accL[j]; a1 += accH[j]; }
    float w = in_norm[d];
    unsigned int pk = (unsigned int)f2bf(a0 * w) | ((unsigned int)f2bf(a1 * w) << 16);
    *(unsigned int*)(aggb + (size_t)d * 128 + col) = pk;
}

// ---- fused GEMM1+GEMM2: z = relu(agg1b@W1+b1) -> z_out; zs=bf16(z*out_norm)
// via wave-private LDS tile (stride 132: conflict-free both directions); tb=bf16(zs@W2).
__global__ __launch_bounds__(256) void k_gemm12(const unsigned short* __restrict__ Ab,
                                                const unsigned short* __restrict__ Wp1,
                                                const unsigned short* __restrict__ Wp2,
                                                const float* __restrict__ bias1,
                                                const float* __restrict__ out_norm,
                                                float* __restrict__ z_out,
                                                unsigned short* __restrict__ tb) {
    __shared__ __align__(16) unsigned short lds1[16 * 128 * 8];   // 32 KB packed W1
    __shared__ __align__(16) unsigned short lds2[16 * 64 * 8];    // 16 KB packed W2
    __shared__ __align__(16) unsigned short zt[64 * 132];         // 16.5 KB zs tile
    {
        const uint4* s1 = (const uint4*)Wp1; uint4* d1 = (uint4*)lds1;
        for (int i = threadIdx.x; i < 2048; i += 256) d1[i] = s1[i];
        const uint4* s2 = (const uint4*)Wp2; uint4* d2 = (uint4*)lds2;
        for (int i = threadIdx.x; i < 1024; i += 256) d2[i] = s2[i];
    }
    __syncthreads();
    int wave = threadIdx.x >> 6, lane = threadIdx.x & 63;
    int base = (blockIdx.x * 4 + wave) * 16;
    if (base >= N_NODES) return;
    int m = lane & 15, q = lane >> 4;
    short8 a[4];
#pragma unroll
    for (int t = 0; t < 4; t++) a[t] = *(const short8*)(Ab + (size_t)(base + m) * 128 + t * 32 + q * 8);
    f32x4 acc[8];
#pragma unroll
    for (int c = 0; c < 8; c++) acc[c] = (f32x4)(0.f);
#pragma unroll
    for (int ct = 0; ct < 8; ct++) {
#pragma unroll
        for (int t = 0; t < 4; t++) {
            short8 b = *(const short8*)(lds1 + ((t * 4 + q) * 128 + ct * 16 + m) * 8);
            acc[ct] = __builtin_amdgcn_mfma_f32_16x16x32_bf16(a[t], b, acc[ct], 0, 0, 0);
        }
    }
    float onr[4];
#pragma unroll
    for (int i = 0; i < 4; i++) onr[i] = out_norm[base + q * 4 + i];
#pragma unroll
    for (int ct = 0; ct < 8; ct++) {
        int col = ct * 16 + m;
        float bv = bias1[col];
#pragma unroll
        for (int i = 0; i < 4; i++) {
            int row = base + q * 4 + i;
            float v = acc[ct][i] + bv;
            v = v > 0.f ? v : 0.f;
            z_out[(size_t)row * 128 + col] = v;
            zt[(wave * 16 + q * 4 + i) * 132 + col] = f2bf(v * onr[i]);
        }
    }
    // zt rows wave-private; intra-wave lgkmcnt suffices, no barrier.
    short8 a2[4];
#pragma unroll
    for (int t = 0; t < 4; t++) a2[t] = *(const short8*)(zt + (wave * 16 + m) * 132 + t * 32 + q * 8);
    f32x4 acc2[4];
#pragma unroll
    for (int c = 0; c < 4; c++) acc2[c] = (f32x4)(0.f);
#pragma unroll
    for (int ct = 0; ct < 4; ct++) {
#pragma unroll
        for (int t = 0; t < 4; t++) {
            short8 b = *(const short8*)(lds2 + ((t * 4 + q) * 64 + ct * 16 + m) * 8);
            acc2[ct] = __builtin_amdgcn_mfma_f32_16x16x32_bf16(a2[t], b, acc2[ct], 0, 0, 0);
        }
    }
#pragma unroll
    for (int ct = 0; ct < 4; ct++) {
        int col = ct * 16 + m;
#pragma unroll
        for (int i = 0; i < 4; i++) {
            int row = base + q * 4 + i;
            tb[(size_t)row * 64 + col] = f2bf(acc2[ct][i]);
        }
    }
}

// ---- layer-2 aggregation: wave per dst node, 64 bf16 cols (1/lane), f32 accum ----
// 8-deep unroll; 128 B contiguous per edge-instruction.
__global__ __launch_bounds__(256) void k_agg2(const unsigned short* __restrict__ tb,
                                              const int* __restrict__ row_ptr, const int* __restrict__ csr,
                                              const float* __restrict__ in_norm, const float* __restrict__ b2,
                                              float* __restrict__ out_h2) {
    int wave = threadIdx.x >> 6, lane = threadIdx.x & 63;
    int d = blockIdx.x * 4 + wave;
    if (d >= N_NODES) return;
    int e0 = __builtin_amdgcn_readfirstlane(row_ptr[d]);
    int e1 = __builtin_amdgcn_readfirstlane(row_ptr[d + 1]);
    float acc[8];
#pragma unroll
    for (int j = 0; j < 8; j++) acc[j] = 0.f;
    int e = e0;
    for (; e + 8 <= e1; e += 8) {
        int sI[8];
#pragma unroll
        for (int j = 0; j < 8; j++) sI[j] = __builtin_amdgcn_readfirstlane(csr[e + j]);
        unsigned short v[8];
#pragma unroll
        for (int j = 0; j < 8; j++) v[j] = tb[(size_t)sI[j] * 64 + lane];
#pragma unroll
        for (int j = 0; j < 8; j++) acc[j] += bf2f(v[j]);
    }
    for (; e < e1; e++) {
        int s = __builtin_amdgcn_readfirstlane(csr[e]);
        acc[0] += bf2f(tb[(size_t)s * 64 + lane]);
    }
    float a = 0.f;
#pragma unroll
    for (int j = 0; j < 8; j++) a += acc[j];
    out_h2[(size_t)d * 64 + lane] = a * in_norm[d] + b2[lane];
}

extern "C" void kernel_launch(void* const* d_in, const int* in_sizes, int n_in,
                              void* d_out, int out_size, void* d_ws, size_t ws_size,
                              hipStream_t stream) {
    const float* x   = (const float*)d_in[0];
    const int*   src = (const int*)d_in[1];
    const int*   dst = (const int*)d_in[2];
    const float* W1  = (const float*)d_in[3];
    const float* b1  = (const float*)d_in[4];
    const float* W2  = (const float*)d_in[5];
    const float* b2  = (const float*)d_in[6];
    float* out_h2 = (float*)d_out;                     // [N,64]
    float* out_z  = (float*)d_out + N_NODES * 64;      // [N,128]

    char* ws = (char*)d_ws;
    size_t off = 0;
    auto alloc = [&](size_t bytes) -> char* {
        char* p = ws + off;
        off = (off + bytes + 255) & ~(size_t)255;
        return p;
    };
    int* gcurD    = (int*)alloc(NB * 4);
    int* gcurS    = (int*)alloc(NB * 4);
    int* bbase    = (int*)alloc((NB + 1) * 4);
    int* row_ptr  = (int*)alloc((N_NODES + 1) * 4);
    float* out_norm = (float*)alloc(N_NODES * 4);
    float* in_norm  = (float*)alloc(N_NODES * 4);
    unsigned int* ebuf = (unsigned int*)alloc((size_t)NB * BCAP * 4);        // 8.0 MB
    unsigned char* ebufS = (unsigned char*)alloc((size_t)NB * BCAP);         // 2.0 MB
    int* csr_src  = (int*)alloc((size_t)N_EDGES * 4);
    unsigned short* Wp1 = (unsigned short*)alloc(2048 * 8 * 2);
    unsigned short* Wp2 = (unsigned short*)alloc(1024 * 8 * 2);
    unsigned short* xb    = (unsigned short*)alloc((size_t)N_NODES * 128 * 2);
    unsigned short* agg1b = (unsigned short*)alloc((size_t)N_NODES * 128 * 2);
    unsigned short* tb    = (unsigned short*)alloc((size_t)N_NODES * 64 * 2);  // bf16 t
    (void)ws_size; (void)in_sizes; (void)n_in; (void)out_size;

    hipMemsetAsync(gcurD, 0, NB * 4, stream);
    hipMemsetAsync(gcurS, 0, NB * 4, stream);

    const int GD_AGG = (N_NODES + 3) / 4;       // 25000
    const int GD_GEMM = (N_NODES / 16 + 3) / 4; // 1563
    const int GD_XB = N_NODES * 32 / 256;       // 12500

    k_part<<<PART_BLOCKS + 12, 256, 0, stream>>>(src, dst, gcurD, gcurS, ebuf, ebufS, W1, W2, Wp1, Wp2);
    k_bhist_scan<<<NB + 1, 256, 0, stream>>>(ebufS, gcurS, out_norm, gcurD, bbase, row_ptr);
    k_bsort_xb<<<NB + GD_XB, 256, 0, stream>>>(ebuf, gcurD, bbase, csr_src, row_ptr, in_norm, x, out_norm, xb);
    k_agg1<<<GD_AGG, 256, 0, stream>>>(xb, row_ptr, csr_src, in_norm, agg1b);
    k_gemm12<<<GD_GEMM, 256, 0, stream>>>(agg1b, Wp1, Wp2, b1, out_norm, out_z, tb);
    k_agg2<<<GD_AGG, 256, 0, stream>>>(tb, row_ptr, csr_src, in_norm, b2, out_h2);
}